// Round 4
// baseline (626.155 us; speedup 1.0000x reference)
//
#include <hip/hip_runtime.h>
#include <hip/hip_bf16.h>
#include <cstdint>

#define E_DIM   1280
#define NHEADS  20
#define HDIM    64
#define QKV_LD  3840   // 3*E

typedef __attribute__((ext_vector_type(8))) short bf8_t;   // 8 bf16 (4 VGPRs)
typedef __attribute__((ext_vector_type(4))) short bf4_t;   // 4 bf16 (2 VGPRs)
typedef __attribute__((ext_vector_type(4))) float f4_t;    // MFMA accumulator

__device__ __forceinline__ short f2bs(float f) {
    union { __hip_bfloat16 h; short s; } u;
    u.h = __float2bfloat16(f);
    return u.s;
}

__device__ __forceinline__ f4_t mfma16x32(bf8_t a, bf8_t b, f4_t c) {
    return __builtin_amdgcn_mfma_f32_16x16x32_bf16(a, b, c, 0, 0, 0);
}
__device__ __forceinline__ f4_t mfma16x16(bf4_t a, bf4_t b, f4_t c) {
    return __builtin_amdgcn_mfma_f32_16x16x16bf16_1k(a, b, c, 0, 0, 0);
}

// async global->LDS, 16B per lane. LDS dest is wave-uniform base + lane*16.
__device__ __forceinline__ void gl_lds16(const void* g, void* l) {
    auto gp = reinterpret_cast<__attribute__((address_space(1))) unsigned int*>(
        reinterpret_cast<uintptr_t>(g));
    auto lp = reinterpret_cast<__attribute__((address_space(3))) unsigned int*>(
        reinterpret_cast<uintptr_t>(l));
    __builtin_amdgcn_global_load_lds(gp, lp, 16, 0, 0);
}

// ---------------- prep: casts + weight concat + bias concat ----------------
// Wq/bq scale = d^-0.5 * log2(e): softmax computed in base-2 domain (exp2f).
#define QSCALE 0.18033688011112042f

__device__ __forceinline__ void cvt8(__hip_bfloat16* dst, const float* src, float sc) {
    float4 a = *(const float4*)src;
    float4 b = *(const float4*)(src + 4);
    bf8_t v;
    v[0] = f2bs(a.x * sc); v[1] = f2bs(a.y * sc); v[2] = f2bs(a.z * sc); v[3] = f2bs(a.w * sc);
    v[4] = f2bs(b.x * sc); v[5] = f2bs(b.y * sc); v[6] = f2bs(b.z * sc); v[7] = f2bs(b.w * sc);
    *(bf8_t*)dst = v;
}

__global__ __launch_bounds__(256) void prep_kernel(
    const float* __restrict__ x,
    const float* __restrict__ wq, const float* __restrict__ wk,
    const float* __restrict__ wv, const float* __restrict__ wo,
    const float* __restrict__ bq, const float* __restrict__ bk, const float* __restrict__ bv,
    __hip_bfloat16* __restrict__ xbf, __hip_bfloat16* __restrict__ wqkv,
    __hip_bfloat16* __restrict__ wobf, float* __restrict__ bqkv,
    long nx8, long nw8, long nb8)
{
    long u = (long)blockIdx.x * 256 + threadIdx.x;
    if (u < nx8) { cvt8(xbf + u * 8, x + u * 8, 1.0f); return; }
    u -= nx8;
    if (u < 3 * nw8) {
        long e = u * 8;
        long w1 = nw8 * 8;
        const float* src; float sc;
        if (e < w1)            { src = wq + e;           sc = QSCALE; }
        else if (e < 2 * w1)   { src = wk + (e - w1);    sc = 1.0f; }
        else                   { src = wv + (e - 2*w1);  sc = 1.0f; }
        cvt8(wqkv + e, src, sc);
        return;
    }
    u -= 3 * nw8;
    if (u < nw8) { cvt8(wobf + u * 8, wo + u * 8, 1.0f); return; }
    u -= nw8;
    if (u < nb8) {
        long e = u * 8;
        #pragma unroll
        for (int j = 0; j < 8; j++) {
            long i = e + j;
            float v;
            if (i < E_DIM)           v = bq[i] * QSCALE;
            else if (i < 2 * E_DIM)  v = bk[i - E_DIM];
            else                     v = bv[i - 2 * E_DIM];
            bqkv[i] = v;
        }
    }
}

// ---------------- m97-style NT GEMM: C = A(MxK) * B(NxK)^T + bias ----------------
template<bool BF16_OUT>
__global__ __launch_bounds__(256, 3) void gemm_nt(
    const __hip_bfloat16* __restrict__ A, const __hip_bfloat16* __restrict__ Bw,
    const float* __restrict__ bias, void* __restrict__ Cout,
    int M, int N, int K, int ldc)
{
    __shared__ __align__(16) __hip_bfloat16 As[128 * 32];
    __shared__ __align__(16) __hip_bfloat16 Bs[128 * 32];
    const int t = threadIdx.x;
    const int wv = t >> 6;
    const int ln = t & 63;
    const int m16 = ln & 15, q4 = ln >> 4;
    const int row0 = blockIdx.y * 128, col0 = blockIdx.x * 128;
    const int wm = (wv >> 1) * 64, wn = (wv & 1) * 64;

    f4_t acc[4][4] = {};

    for (int k0 = 0; k0 < K; k0 += 32) {
        #pragma unroll
        for (int i = 0; i < 2; i++) {
            int s = i * 256 + t;
            int r = s >> 2, c = s & 3;
            gl_lds16(A + (size_t)(row0 + r) * K + k0 + c * 8,
                     As + (size_t)(i * 256 + wv * 64) * 8);
        }
        #pragma unroll
        for (int i = 0; i < 2; i++) {
            int s = i * 256 + t;
            int r = s >> 2, c = s & 3;
            gl_lds16(Bw + (size_t)(col0 + r) * K + k0 + c * 8,
                     Bs + (size_t)(i * 256 + wv * 64) * 8);
        }
        __syncthreads();
        bf8_t af[4], bfr[4];
        #pragma unroll
        for (int mt = 0; mt < 4; mt++)
            af[mt] = *(const bf8_t*)&As[(wm + mt * 16 + m16) * 32 + q4 * 8];
        #pragma unroll
        for (int nt = 0; nt < 4; nt++)
            bfr[nt] = *(const bf8_t*)&Bs[(wn + nt * 16 + m16) * 32 + q4 * 8];
        #pragma unroll
        for (int mt = 0; mt < 4; mt++)
            #pragma unroll
            for (int nt = 0; nt < 4; nt++)
                acc[mt][nt] = mfma16x32(af[mt], bfr[nt], acc[mt][nt]);
        __syncthreads();
    }

    #pragma unroll
    for (int nt = 0; nt < 4; nt++) {
        int cg = col0 + wn + nt * 16 + m16;
        float bv = bias[cg];
        #pragma unroll
        for (int mt = 0; mt < 4; mt++) {
            #pragma unroll
            for (int r = 0; r < 4; r++) {
                int rg = row0 + wm + mt * 16 + q4 * 4 + r;
                float v = acc[mt][nt][r] + bv;
                if constexpr (BF16_OUT)
                    ((__hip_bfloat16*)Cout)[(long)rg * ldc + cg] = __float2bfloat16(v);
                else
                    ((float*)Cout)[(long)rg * ldc + cg] = v;
            }
        }
    }
}

// ---------------- RoPE (in place on q,k sections of qkv) ----------------
__global__ __launch_bounds__(256) void rope_kernel(
    __hip_bfloat16* __restrict__ qkv, const int* __restrict__ cu, int B, int T)
{
    long idx = (long)blockIdx.x * 256 + threadIdx.x;
    int i = idx & 31;
    long r = idx >> 5;
    int h = (int)(r % NHEADS);
    int tok = (int)(r / NHEADS);
    if (tok >= T) return;
    int pos = tok;
    for (int b = 1; b <= B; b++) if (tok >= cu[b]) pos = tok - cu[b];
    float f = (float)pos * exp2f(-(float)i * 0.41524100558003436f);
    float s, c;
    sincosf(f, &s, &c);
    long base = (long)tok * QKV_LD + h * HDIM + i;
    {
        float q1 = __bfloat162float(qkv[base]);
        float q2 = __bfloat162float(qkv[base + 32]);
        qkv[base]      = __float2bfloat16(q1 * c - q2 * s);
        qkv[base + 32] = __float2bfloat16(q2 * c + q1 * s);
    }
    {
        long kb = base + E_DIM;
        float k1 = __bfloat162float(qkv[kb]);
        float k2 = __bfloat162float(qkv[kb + 32]);
        qkv[kb]      = __float2bfloat16(k1 * c - k2 * s);
        qkv[kb + 32] = __float2bfloat16(k2 * c + k1 * s);
    }
}

// ---------------- V transpose: (T, h, d) -> (h*d, T) ----------------
__global__ __launch_bounds__(256) void vtrans_kernel(
    const __hip_bfloat16* __restrict__ qkv, __hip_bfloat16* __restrict__ vt, int T)
{
    long u = (long)blockIdx.x * 256 + threadIdx.x;
    int tchunks = T >> 3;
    int tc = (int)(u % tchunks);
    int hd = (int)(u / tchunks);
    if (hd >= E_DIM) return;
    long t0 = (long)tc * 8;
    bf8_t v;
    #pragma unroll
    for (int j = 0; j < 8; j++)
        v[j] = *(const short*)&qkv[(t0 + j) * QKV_LD + 2 * E_DIM + hd];
    *(bf8_t*)&vt[(long)hd * T + t0] = v;
}

// ---------------- flash attention, operand-swapped + swizzled + XCD-local ----------------
// Work item = (pair=(seq,head), q-tile of 128 rows). XCD j (blockIdx%8) owns pairs
// p == j (mod 8); a pair's q-tiles sit in consecutive slots, so co-resident blocks
// on one XCD share few KV sets (~3.5 MB < 4 MiB per-XCD L2).
// S^T = K.Q^T; P^T feeds O^T = V^T.P^T from registers. K/V staged via
// global_load_lds with XOR chunk swizzle (conflict-free fragment reads).
// Epilogue bounces O^T through LDS for full-cacheline 16B/lane stores.
__global__ __launch_bounds__(256, 4) void attn_kernel(
    const __hip_bfloat16* __restrict__ qkv, const __hip_bfloat16* __restrict__ vt,
    const int* __restrict__ cu, __hip_bfloat16* __restrict__ obuf, int B, int T)
{
    __shared__ __align__(16) __hip_bfloat16 smem[128 * 64 + 64 * 128];  // 32 KB
    __hip_bfloat16* Ks = smem;               // [key][d] swizzled, 16 KB
    __hip_bfloat16* Vs = smem + 128 * 64;    // [d][key] swizzled, 16 KB

    // XCD-aware work mapping
    int j = blockIdx.x & 7;
    int s = blockIdx.x >> 3;
    int b = 0, h = j;
    int l = 0, seq0 = 0, q0 = -1;
    for (int p = j; p < B * NHEADS; p += 8) {
        seq0 = cu[b];
        l = cu[b + 1] - seq0;
        int ntile = (l + 127) >> 7;
        if (s < ntile) { q0 = s * 128; break; }
        s -= ntile;
        h += 8;
        if (h >= NHEADS) { h -= NHEADS; b += 1; }
    }
    if (q0 < 0) return;

    const int t = threadIdx.x;
    const int wv = t >> 6, ln = t & 63;
    const int m16 = ln & 15, q4 = ln >> 4;

    // Q B-frags in registers: bq[nt][kc] = B[k=kc*32+q4*8+j][n=m16]
    bf8_t bq[2][2];
    #pragma unroll
    for (int nt = 0; nt < 2; nt++) {
        int qrow = q0 + wv * 32 + nt * 16 + m16;
        #pragma unroll
        for (int kc = 0; kc < 2; kc++) {
            bf8_t v = (bf8_t)0;
            if (qrow < l)
                v = *(const bf8_t*)(qkv + (long)(seq0 + qrow) * QKV_LD + h * HDIM + kc * 32 + q4 * 8);
            bq[nt][kc] = v;
        }
    }

    f4_t oacc[2][4] = {};
    float m_s[2] = {-1e30f, -1e30f};
    float l_s[2] = {0.0f, 0.0f};

    const int ksw0 = (q4 ^ (m16 & 7)) * 8;        // slot of global chunk q4
    const int ksw1 = ((4 + q4) ^ (m16 & 7)) * 8;  // slot of global chunk 4+q4

    for (int kv0 = 0; kv0 < l; kv0 += 128) {
        bool full = (kv0 + 128 <= l);
        __syncthreads();
        if (full) {
            #pragma unroll
            for (int i = 0; i < 4; i++) {   // K: slot s2 -> row s2>>3, chunk (s2&7)^(row&7)
                int s2 = i * 256 + t;
                int key = s2 >> 3, cg = (s2 & 7) ^ (key & 7);
                gl_lds16(qkv + (long)(seq0 + kv0 + key) * QKV_LD + E_DIM + h * HDIM + cg * 8,
                         (char*)Ks + (size_t)(i * 256 + wv * 64) * 16);
            }
            #pragma unroll
            for (int i = 0; i < 4; i++) {   // V: slot s2 -> row s2>>4, chunk (s2&15)^(row&15)
                int s2 = i * 256 + t;
                int d = s2 >> 4, cg = (s2 & 15) ^ (d & 15);
                gl_lds16(vt + (long)(h * HDIM + d) * T + seq0 + kv0 + cg * 8,
                         (char*)Vs + (size_t)(i * 256 + wv * 64) * 16);
            }
        } else {
            #pragma unroll
            for (int i = 0; i < 4; i++) {
                int s2 = i * 256 + t;
                int key = s2 >> 3, c = s2 & 7;
                bf8_t v = (bf8_t)0;
                if (kv0 + key < l)
                    v = *(const bf8_t*)(qkv + (long)(seq0 + kv0 + key) * QKV_LD + E_DIM + h * HDIM + c * 8);
                *(bf8_t*)&Ks[key * 64 + (c ^ (key & 7)) * 8] = v;
            }
            #pragma unroll
            for (int i = 0; i < 4; i++) {
                int s2 = i * 256 + t;
                int d = s2 >> 4, c = s2 & 15;
                bf8_t v = (bf8_t)0;
                int tb = kv0 + c * 8;
                #pragma unroll
                for (int u = 0; u < 8; u++)
                    if (tb + u < l)
                        v[u] = *(const short*)&vt[(long)(h * HDIM + d) * T + seq0 + tb + u];
                *(bf8_t*)&Vs[d * 128 + (c ^ (d & 15)) * 8] = v;
            }
        }
        __syncthreads();

        // S^T = K.Q^T : S[nt][mt] holds S^T[key=mt*16+q4*4+r][qrow=m16]
        f4_t S[2][8];
        #pragma unroll
        for (int mt = 0; mt < 8; mt++) {
            const __hip_bfloat16* krow = &Ks[(mt * 16 + m16) * 64];
            bf8_t ak0 = *(const bf8_t*)(krow + ksw0);
            bf8_t ak1 = *(const bf8_t*)(krow + ksw1);
            #pragma unroll
            for (int nt = 0; nt < 2; nt++) {
                f4_t a = {};
                a = mfma16x32(ak0, bq[nt][0], a);
                a = mfma16x32(ak1, bq[nt][1], a);
                S[nt][mt] = a;
            }
        }
        if (!full) {
            #pragma unroll
            for (int mt = 0; mt < 8; mt++) {
                #pragma unroll
                for (int r = 0; r < 4; r++) {
                    bool valid = (kv0 + mt * 16 + q4 * 4 + r) < l;
                    #pragma unroll
                    for (int nt = 0; nt < 2; nt++)
                        if (!valid) S[nt][mt][r] = -1e30f;
                }
            }
        }

        // online softmax (base-2 domain; log2e folded into Wq/bq)
        #pragma unroll
        for (int nt = 0; nt < 2; nt++) {
            float mx = -1e30f;
            #pragma unroll
            for (int mt = 0; mt < 8; mt++)
                #pragma unroll
                for (int r = 0; r < 4; r++)
                    mx = fmaxf(mx, S[nt][mt][r]);
            mx = fmaxf(mx, __shfl_xor(mx, 16));
            mx = fmaxf(mx, __shfl_xor(mx, 32));
            float mn = fmaxf(m_s[nt], mx);
            float al = exp2f(m_s[nt] - mn);
            m_s[nt] = mn;
            float ls = 0.0f;
            #pragma unroll
            for (int mt = 0; mt < 8; mt++) {
                #pragma unroll
                for (int r = 0; r < 4; r++) {
                    float p = exp2f(S[nt][mt][r] - mn);
                    ls += p;
                    S[nt][mt][r] = p;
                }
            }
            l_s[nt] = l_s[nt] * al + ls;
            #pragma unroll
            for (int dt = 0; dt < 4; dt++)
                #pragma unroll
                for (int r = 0; r < 4; r++)
                    oacc[nt][dt][r] *= al;
        }

        // O^T += V^T . P^T  (A=V^T from swizzled LDS, B=P^T from regs)
        #pragma unroll
        for (int mt = 0; mt < 8; mt++) {
            bf4_t bp[2];
            #pragma unroll
            for (int nt = 0; nt < 2; nt++) {
                bf4_t p;
                p[0] = f2bs(S[nt][mt][0]); p[1] = f2bs(S[nt][mt][1]);
                p[2] = f2bs(S[nt][mt][2]); p[3] = f2bs(S[nt][mt][3]);
                bp[nt] = p;
            }
            const int vsw = ((mt * 2 + (q4 >> 1)) ^ m16) * 8 + (q4 & 1) * 4;
            #pragma unroll
            for (int dt = 0; dt < 4; dt++) {
                bf4_t av = *(const bf4_t*)&Vs[(dt * 16 + m16) * 128 + vsw];
                #pragma unroll
                for (int nt = 0; nt < 2; nt++)
                    oacc[nt][dt] = mfma16x16(av, bp[nt], oacc[nt][dt]);
            }
        }
    }

    // finalize: normalize, transpose O^T -> O through LDS, full-line stores
    __syncthreads();  // all waves done with Ks/Vs; repurpose smem
    __hip_bfloat16* Os = smem;  // [row][d], stride 72 (16B-aligned rows, low-conflict)
    #pragma unroll
    for (int nt = 0; nt < 2; nt++) {
        float ls = l_s[nt];
        ls += __shfl_xor(ls, 16);
        ls += __shfl_xor(ls, 32);
        float inv = 1.0f / ls;
        int rl = wv * 32 + nt * 16 + m16;
        #pragma unroll
        for (int dt = 0; dt < 4; dt++) {
            bf4_t o;
            #pragma unroll
            for (int r = 0; r < 4; r++)
                o[r] = f2bs(oacc[nt][dt][r] * inv);
            *(bf4_t*)&Os[rl * 72 + dt * 16 + q4 * 4] = o;
        }
    }
    __syncthreads();
    #pragma unroll
    for (int i = 0; i < 4; i++) {
        int s2 = i * 256 + t;
        int row = s2 >> 3, c = s2 & 7;
        if (q0 + row < l) {
            bf8_t v = *(const bf8_t*)&Os[row * 72 + c * 8];
            *(bf8_t*)&obuf[(long)(seq0 + q0 + row) * E_DIM + h * HDIM + c * 8] = v;
        }
    }
}

// ---------------- launch ----------------
extern "C" void kernel_launch(void* const* d_in, const int* in_sizes, int n_in,
                              void* d_out, int out_size, void* d_ws, size_t ws_size,
                              hipStream_t stream) {
    const int E = E_DIM;
    const int T = in_sizes[0] / E;      // 8192
    const int B = in_sizes[1] - 1;      // 8

    const float* x  = (const float*)d_in[0];
    const int*   cu = (const int*)d_in[1];
    const float* Wq = (const float*)d_in[3];
    const float* bq = (const float*)d_in[4];
    const float* Wk = (const float*)d_in[5];
    const float* bk = (const float*)d_in[6];
    const float* Wv = (const float*)d_in[7];
    const float* bv = (const float*)d_in[8];
    const float* Wo = (const float*)d_in[9];
    const float* bo = (const float*)d_in[10];

    char* ws = (char*)d_ws;
    size_t off = 0;
    auto alloc = [&](size_t bytes) -> void* {
        void* p = ws + off;
        off = (off + bytes + 255) & ~(size_t)255;
        return p;
    };
    __hip_bfloat16* xbf   = (__hip_bfloat16*)alloc((size_t)T * E * 2);
    __hip_bfloat16* wqkv  = (__hip_bfloat16*)alloc((size_t)3 * E * E * 2);
    __hip_bfloat16* wobf  = (__hip_bfloat16*)alloc((size_t)E * E * 2);
    float*          bqkv  = (float*)alloc((size_t)3 * E * 4);
    __hip_bfloat16* qkvb  = (__hip_bfloat16*)alloc((size_t)T * 3 * E * 2);
    __hip_bfloat16* vt    = (__hip_bfloat16*)alloc((size_t)E * T * 2);
    __hip_bfloat16* obuf  = xbf;  // alias: x_bf dead after QKV GEMM

    long nx8 = (long)T * E / 8;
    long nw8 = (long)E * E / 8;
    long nb8 = (long)3 * E / 8;
    long total = nx8 + 4 * nw8 + nb8;
    int pblocks = (int)((total + 255) / 256);
    prep_kernel<<<pblocks, 256, 0, stream>>>(x, Wq, Wk, Wv, Wo, bq, bk, bv,
                                             xbf, wqkv, wobf, bqkv, nx8, nw8, nb8);

    gemm_nt<true><<<dim3(3 * E / 128, T / 128), 256, 0, stream>>>(
        xbf, wqkv, bqkv, qkvb, T, 3 * E, E, 3 * E);

    rope_kernel<<<(int)(((long)T * NHEADS * 32) / 256), 256, 0, stream>>>(qkvb, cu, B, T);

    vtrans_kernel<<<(int)(((long)E * T / 8 + 255) / 256), 256, 0, stream>>>(qkvb, vt, T);

    // 8 XCD lanes x per-XCD slot upper bound (<= 3 head-residues per seq per XCD)
    int slots_ub = 3 * (T / 128 + B);
    attn_kernel<<<8 * slots_ub, 256, 0, stream>>>(qkvb, vt, cu, obuf, B, T);

    gemm_nt<false><<<dim3(E / 128, T / 128), 256, 0, stream>>>(
        obuf, wobf, bo, d_out, T, E, E, E);
}

// Round 5
// 571.223 us; speedup vs baseline: 1.0962x; 1.0962x over previous
//
#include <hip/hip_runtime.h>
#include <hip/hip_bf16.h>
#include <cstdint>

#define E_DIM   1280
#define NHEADS  20
#define HDIM    64
#define QKV_LD  3840   // 3*E

typedef __attribute__((ext_vector_type(8))) short bf8_t;   // 8 bf16 (4 VGPRs)
typedef __attribute__((ext_vector_type(4))) short bf4_t;   // 4 bf16 (2 VGPRs)
typedef __attribute__((ext_vector_type(4))) float f4_t;    // MFMA accumulator

__device__ __forceinline__ short f2bs(float f) {
    union { __hip_bfloat16 h; short s; } u;
    u.h = __float2bfloat16(f);
    return u.s;
}

__device__ __forceinline__ f4_t mfma16x32(bf8_t a, bf8_t b, f4_t c) {
    return __builtin_amdgcn_mfma_f32_16x16x32_bf16(a, b, c, 0, 0, 0);
}
__device__ __forceinline__ f4_t mfma16x16(bf4_t a, bf4_t b, f4_t c) {
    return __builtin_amdgcn_mfma_f32_16x16x16bf16_1k(a, b, c, 0, 0, 0);
}

// async global->LDS, 16B per lane. LDS dest is wave-uniform base + lane*16.
__device__ __forceinline__ void gl_lds16(const void* g, void* l) {
    auto gp = reinterpret_cast<__attribute__((address_space(1))) unsigned int*>(
        reinterpret_cast<uintptr_t>(g));
    auto lp = reinterpret_cast<__attribute__((address_space(3))) unsigned int*>(
        reinterpret_cast<uintptr_t>(l));
    __builtin_amdgcn_global_load_lds(gp, lp, 16, 0, 0);
}

// ---------------- prep: casts + weight concat + bias concat ----------------
// Wq/bq scale = d^-0.5 * log2(e): softmax computed in base-2 domain (exp2f).
#define QSCALE 0.18033688011112042f

__device__ __forceinline__ void cvt8(__hip_bfloat16* dst, const float* src, float sc) {
    float4 a = *(const float4*)src;
    float4 b = *(const float4*)(src + 4);
    bf8_t v;
    v[0] = f2bs(a.x * sc); v[1] = f2bs(a.y * sc); v[2] = f2bs(a.z * sc); v[3] = f2bs(a.w * sc);
    v[4] = f2bs(b.x * sc); v[5] = f2bs(b.y * sc); v[6] = f2bs(b.z * sc); v[7] = f2bs(b.w * sc);
    *(bf8_t*)dst = v;
}

__global__ __launch_bounds__(256) void prep_kernel(
    const float* __restrict__ x,
    const float* __restrict__ wq, const float* __restrict__ wk,
    const float* __restrict__ wv, const float* __restrict__ wo,
    const float* __restrict__ bq, const float* __restrict__ bk, const float* __restrict__ bv,
    __hip_bfloat16* __restrict__ xbf, __hip_bfloat16* __restrict__ wqkv,
    __hip_bfloat16* __restrict__ wobf, float* __restrict__ bqkv,
    long nx8, long nw8, long nb8)
{
    long u = (long)blockIdx.x * 256 + threadIdx.x;
    if (u < nx8) { cvt8(xbf + u * 8, x + u * 8, 1.0f); return; }
    u -= nx8;
    if (u < 3 * nw8) {
        long e = u * 8;
        long w1 = nw8 * 8;
        const float* src; float sc;
        if (e < w1)            { src = wq + e;           sc = QSCALE; }
        else if (e < 2 * w1)   { src = wk + (e - w1);    sc = 1.0f; }
        else                   { src = wv + (e - 2*w1);  sc = 1.0f; }
        cvt8(wqkv + e, src, sc);
        return;
    }
    u -= 3 * nw8;
    if (u < nw8) { cvt8(wobf + u * 8, wo + u * 8, 1.0f); return; }
    u -= nw8;
    if (u < nb8) {
        long e = u * 8;
        #pragma unroll
        for (int j = 0; j < 8; j++) {
            long i = e + j;
            float v;
            if (i < E_DIM)           v = bq[i] * QSCALE;
            else if (i < 2 * E_DIM)  v = bk[i - E_DIM];
            else                     v = bv[i - 2 * E_DIM];
            bqkv[i] = v;
        }
    }
}

// ---------------- m97-style NT GEMM: C = A(MxK) * B(NxK)^T + bias ----------------
template<bool BF16_OUT>
__global__ __launch_bounds__(256, 3) void gemm_nt(
    const __hip_bfloat16* __restrict__ A, const __hip_bfloat16* __restrict__ Bw,
    const float* __restrict__ bias, void* __restrict__ Cout,
    int M, int N, int K, int ldc)
{
    __shared__ __align__(16) __hip_bfloat16 As[128 * 32];
    __shared__ __align__(16) __hip_bfloat16 Bs[128 * 32];
    const int t = threadIdx.x;
    const int wv = t >> 6;
    const int ln = t & 63;
    const int m16 = ln & 15, q4 = ln >> 4;
    const int row0 = blockIdx.y * 128, col0 = blockIdx.x * 128;
    const int wm = (wv >> 1) * 64, wn = (wv & 1) * 64;

    f4_t acc[4][4] = {};

    for (int k0 = 0; k0 < K; k0 += 32) {
        #pragma unroll
        for (int i = 0; i < 2; i++) {
            int s = i * 256 + t;
            int r = s >> 2, c = s & 3;
            gl_lds16(A + (size_t)(row0 + r) * K + k0 + c * 8,
                     As + (size_t)(i * 256 + wv * 64) * 8);
        }
        #pragma unroll
        for (int i = 0; i < 2; i++) {
            int s = i * 256 + t;
            int r = s >> 2, c = s & 3;
            gl_lds16(Bw + (size_t)(col0 + r) * K + k0 + c * 8,
                     Bs + (size_t)(i * 256 + wv * 64) * 8);
        }
        __syncthreads();
        bf8_t af[4], bfr[4];
        #pragma unroll
        for (int mt = 0; mt < 4; mt++)
            af[mt] = *(const bf8_t*)&As[(wm + mt * 16 + m16) * 32 + q4 * 8];
        #pragma unroll
        for (int nt = 0; nt < 4; nt++)
            bfr[nt] = *(const bf8_t*)&Bs[(wn + nt * 16 + m16) * 32 + q4 * 8];
        #pragma unroll
        for (int mt = 0; mt < 4; mt++)
            #pragma unroll
            for (int nt = 0; nt < 4; nt++)
                acc[mt][nt] = mfma16x32(af[mt], bfr[nt], acc[mt][nt]);
        __syncthreads();
    }

    #pragma unroll
    for (int nt = 0; nt < 4; nt++) {
        int cg = col0 + wn + nt * 16 + m16;
        float bv = bias[cg];
        #pragma unroll
        for (int mt = 0; mt < 4; mt++) {
            #pragma unroll
            for (int r = 0; r < 4; r++) {
                int rg = row0 + wm + mt * 16 + q4 * 4 + r;
                float v = acc[mt][nt][r] + bv;
                if constexpr (BF16_OUT)
                    ((__hip_bfloat16*)Cout)[(long)rg * ldc + cg] = __float2bfloat16(v);
                else
                    ((float*)Cout)[(long)rg * ldc + cg] = v;
            }
        }
    }
}

// ---------------- RoPE (in place on q,k sections of qkv) ----------------
__global__ __launch_bounds__(256) void rope_kernel(
    __hip_bfloat16* __restrict__ qkv, const int* __restrict__ cu, int B, int T)
{
    long idx = (long)blockIdx.x * 256 + threadIdx.x;
    int i = idx & 31;
    long r = idx >> 5;
    int h = (int)(r % NHEADS);
    int tok = (int)(r / NHEADS);
    if (tok >= T) return;
    int pos = tok;
    for (int b = 1; b <= B; b++) if (tok >= cu[b]) pos = tok - cu[b];
    float f = (float)pos * exp2f(-(float)i * 0.41524100558003436f);
    float s, c;
    sincosf(f, &s, &c);
    long base = (long)tok * QKV_LD + h * HDIM + i;
    {
        float q1 = __bfloat162float(qkv[base]);
        float q2 = __bfloat162float(qkv[base + 32]);
        qkv[base]      = __float2bfloat16(q1 * c - q2 * s);
        qkv[base + 32] = __float2bfloat16(q2 * c + q1 * s);
    }
    {
        long kb = base + E_DIM;
        float k1 = __bfloat162float(qkv[kb]);
        float k2 = __bfloat162float(qkv[kb + 32]);
        qkv[kb]      = __float2bfloat16(k1 * c - k2 * s);
        qkv[kb + 32] = __float2bfloat16(k2 * c + k1 * s);
    }
}

// ---------------- V transpose: (T, h, d) -> (h*d, T) ----------------
__global__ __launch_bounds__(256) void vtrans_kernel(
    const __hip_bfloat16* __restrict__ qkv, __hip_bfloat16* __restrict__ vt, int T)
{
    long u = (long)blockIdx.x * 256 + threadIdx.x;
    int tchunks = T >> 3;
    int tc = (int)(u % tchunks);
    int hd = (int)(u / tchunks);
    if (hd >= E_DIM) return;
    long t0 = (long)tc * 8;
    bf8_t v;
    #pragma unroll
    for (int j = 0; j < 8; j++)
        v[j] = *(const short*)&qkv[(t0 + j) * QKV_LD + 2 * E_DIM + hd];
    *(bf8_t*)&vt[(long)hd * T + t0] = v;
}

// ---------------- flash attention: 256-row Q-tiles, 8 waves, swizzled LDS ----------------
// 1 block (512 thr) = 256 q-rows of one (seq, head); wave w owns rows w*32..w*32+31.
// KV re-read volume halves vs 128-row tiles: ~178 MB total -> <30 us HBM even with
// zero L2 hits (structural fix; rounds 3/4 showed L2-scheduling bets don't hold).
// Natural h-fastest block order (round-2 pattern, measured FETCH 74 MB).
// S^T = K.Q^T; P^T feeds O^T = V^T.P^T from registers. K/V staged via
// global_load_lds with XOR chunk swizzle (conflict-free fragment reads).
__global__ __launch_bounds__(512, 4) void attn_kernel(
    const __hip_bfloat16* __restrict__ qkv, const __hip_bfloat16* __restrict__ vt,
    const int* __restrict__ cu, __hip_bfloat16* __restrict__ obuf, int B, int T)
{
    __shared__ __align__(16) __hip_bfloat16 Ks[128 * 64];  // [key][d] swizzled, 16 KB
    __shared__ __align__(16) __hip_bfloat16 Vs[64 * 128];  // [d][key] swizzled, 16 KB

    int idx = blockIdx.x;
    int h = idx % NHEADS;
    int gt = idx / NHEADS;
    int b = 0, l = 0, seq0 = 0;
    for (; b < B; ++b) {
        seq0 = cu[b];
        l = cu[b + 1] - seq0;
        int ntile = (l + 255) >> 8;
        if (gt < ntile) break;
        gt -= ntile;
    }
    if (b == B) return;
    int q0 = gt * 256;

    const int t = threadIdx.x;
    const int wv = t >> 6, ln = t & 63;
    const int m16 = ln & 15, q4 = ln >> 4;

    // Q B-frags in registers: bq[nt][kc] = B[k=kc*32+q4*8+j][n=m16]
    bf8_t bq[2][2];
    #pragma unroll
    for (int nt = 0; nt < 2; nt++) {
        int qrow = q0 + wv * 32 + nt * 16 + m16;
        #pragma unroll
        for (int kc = 0; kc < 2; kc++) {
            bf8_t v = (bf8_t)0;
            if (qrow < l)
                v = *(const bf8_t*)(qkv + (long)(seq0 + qrow) * QKV_LD + h * HDIM + kc * 32 + q4 * 8);
            bq[nt][kc] = v;
        }
    }

    f4_t oacc[2][4] = {};
    float m_s[2] = {-1e30f, -1e30f};
    float l_s[2] = {0.0f, 0.0f};

    const int ksw0 = (q4 ^ (m16 & 7)) * 8;        // slot of global chunk q4
    const int ksw1 = ((4 + q4) ^ (m16 & 7)) * 8;  // slot of global chunk 4+q4

    for (int kv0 = 0; kv0 < l; kv0 += 128) {
        bool full = (kv0 + 128 <= l);
        __syncthreads();
        if (full) {
            #pragma unroll
            for (int i = 0; i < 2; i++) {   // K: slot s2 -> row s2>>3, chunk (s2&7)^(row&7)
                int s2 = i * 512 + t;
                int key = s2 >> 3, cg = (s2 & 7) ^ (key & 7);
                gl_lds16(qkv + (long)(seq0 + kv0 + key) * QKV_LD + E_DIM + h * HDIM + cg * 8,
                         (char*)Ks + (size_t)(i * 512 + wv * 64) * 16);
            }
            #pragma unroll
            for (int i = 0; i < 2; i++) {   // V: slot s2 -> row s2>>4, chunk (s2&15)^(row&15)
                int s2 = i * 512 + t;
                int d = s2 >> 4, cg = (s2 & 15) ^ (d & 15);
                gl_lds16(vt + (long)(h * HDIM + d) * T + seq0 + kv0 + cg * 8,
                         (char*)Vs + (size_t)(i * 512 + wv * 64) * 16);
            }
        } else {
            #pragma unroll
            for (int i = 0; i < 2; i++) {
                int s2 = i * 512 + t;
                int key = s2 >> 3, c = s2 & 7;
                bf8_t v = (bf8_t)0;
                if (kv0 + key < l)
                    v = *(const bf8_t*)(qkv + (long)(seq0 + kv0 + key) * QKV_LD + E_DIM + h * HDIM + c * 8);
                *(bf8_t*)&Ks[key * 64 + (c ^ (key & 7)) * 8] = v;
            }
            #pragma unroll
            for (int i = 0; i < 2; i++) {
                int s2 = i * 512 + t;
                int d = s2 >> 4, c = s2 & 15;
                bf8_t v = (bf8_t)0;
                int tb = kv0 + c * 8;
                #pragma unroll
                for (int u = 0; u < 8; u++)
                    if (tb + u < l)
                        v[u] = *(const short*)&vt[(long)(h * HDIM + d) * T + seq0 + tb + u];
                *(bf8_t*)&Vs[d * 128 + (c ^ (d & 15)) * 8] = v;
            }
        }
        __syncthreads();

        // S^T = K.Q^T : S[nt][mt] holds S^T[key=mt*16+q4*4+r][qrow=m16]
        f4_t S[2][8];
        #pragma unroll
        for (int mt = 0; mt < 8; mt++) {
            const __hip_bfloat16* krow = &Ks[(mt * 16 + m16) * 64];
            bf8_t ak0 = *(const bf8_t*)(krow + ksw0);
            bf8_t ak1 = *(const bf8_t*)(krow + ksw1);
            #pragma unroll
            for (int nt = 0; nt < 2; nt++) {
                f4_t a = {};
                a = mfma16x32(ak0, bq[nt][0], a);
                a = mfma16x32(ak1, bq[nt][1], a);
                S[nt][mt] = a;
            }
        }
        if (!full) {
            #pragma unroll
            for (int mt = 0; mt < 8; mt++) {
                #pragma unroll
                for (int r = 0; r < 4; r++) {
                    bool valid = (kv0 + mt * 16 + q4 * 4 + r) < l;
                    #pragma unroll
                    for (int nt = 0; nt < 2; nt++)
                        if (!valid) S[nt][mt][r] = -1e30f;
                }
            }
        }

        // online softmax (base-2 domain; log2e folded into Wq/bq)
        #pragma unroll
        for (int nt = 0; nt < 2; nt++) {
            float mx = -1e30f;
            #pragma unroll
            for (int mt = 0; mt < 8; mt++)
                #pragma unroll
                for (int r = 0; r < 4; r++)
                    mx = fmaxf(mx, S[nt][mt][r]);
            mx = fmaxf(mx, __shfl_xor(mx, 16));
            mx = fmaxf(mx, __shfl_xor(mx, 32));
            float mn = fmaxf(m_s[nt], mx);
            float al = exp2f(m_s[nt] - mn);
            m_s[nt] = mn;
            float ls = 0.0f;
            #pragma unroll
            for (int mt = 0; mt < 8; mt++) {
                #pragma unroll
                for (int r = 0; r < 4; r++) {
                    float p = exp2f(S[nt][mt][r] - mn);
                    ls += p;
                    S[nt][mt][r] = p;
                }
            }
            l_s[nt] = l_s[nt] * al + ls;
            #pragma unroll
            for (int dt = 0; dt < 4; dt++)
                #pragma unroll
                for (int r = 0; r < 4; r++)
                    oacc[nt][dt][r] *= al;
        }

        // O^T += V^T . P^T  (A=V^T from swizzled LDS, B=P^T from regs)
        #pragma unroll
        for (int mt = 0; mt < 8; mt++) {
            bf4_t bp[2];
            #pragma unroll
            for (int nt = 0; nt < 2; nt++) {
                bf4_t p;
                p[0] = f2bs(S[nt][mt][0]); p[1] = f2bs(S[nt][mt][1]);
                p[2] = f2bs(S[nt][mt][2]); p[3] = f2bs(S[nt][mt][3]);
                bp[nt] = p;
            }
            const int vsw = ((mt * 2 + (q4 >> 1)) ^ m16) * 8 + (q4 & 1) * 4;
            #pragma unroll
            for (int dt = 0; dt < 4; dt++) {
                bf4_t av = *(const bf4_t*)&Vs[(dt * 16 + m16) * 128 + vsw];
                #pragma unroll
                for (int nt = 0; nt < 2; nt++)
                    oacc[nt][dt] = mfma16x16(av, bp[nt], oacc[nt][dt]);
            }
        }
    }

    // finalize
    #pragma unroll
    for (int nt = 0; nt < 2; nt++) {
        float ls = l_s[nt];
        ls += __shfl_xor(ls, 16);
        ls += __shfl_xor(ls, 32);
        float inv = 1.0f / ls;
        int qrow = q0 + wv * 32 + nt * 16 + m16;
        if (qrow < l) {
            #pragma unroll
            for (int dt = 0; dt < 4; dt++) {
                bf4_t o;
                #pragma unroll
                for (int r = 0; r < 4; r++)
                    o[r] = f2bs(oacc[nt][dt][r] * inv);
                *(bf4_t*)&obuf[(long)(seq0 + qrow) * E_DIM + h * HDIM + dt * 16 + q4 * 4] = o;
            }
        }
    }
}

// ---------------- launch ----------------
extern "C" void kernel_launch(void* const* d_in, const int* in_sizes, int n_in,
                              void* d_out, int out_size, void* d_ws, size_t ws_size,
                              hipStream_t stream) {
    const int E = E_DIM;
    const int T = in_sizes[0] / E;      // 8192
    const int B = in_sizes[1] - 1;      // 8

    const float* x  = (const float*)d_in[0];
    const int*   cu = (const int*)d_in[1];
    const float* Wq = (const float*)d_in[3];
    const float* bq = (const float*)d_in[4];
    const float* Wk = (const float*)d_in[5];
    const float* bk = (const float*)d_in[6];
    const float* Wv = (const float*)d_in[7];
    const float* bv = (const float*)d_in[8];
    const float* Wo = (const float*)d_in[9];
    const float* bo = (const float*)d_in[10];

    char* ws = (char*)d_ws;
    size_t off = 0;
    auto alloc = [&](size_t bytes) -> void* {
        void* p = ws + off;
        off = (off + bytes + 255) & ~(size_t)255;
        return p;
    };
    __hip_bfloat16* xbf   = (__hip_bfloat16*)alloc((size_t)T * E * 2);
    __hip_bfloat16* wqkv  = (__hip_bfloat16*)alloc((size_t)3 * E * E * 2);
    __hip_bfloat16* wobf  = (__hip_bfloat16*)alloc((size_t)E * E * 2);
    float*          bqkv  = (float*)alloc((size_t)3 * E * 4);
    __hip_bfloat16* qkvb  = (__hip_bfloat16*)alloc((size_t)T * 3 * E * 2);
    __hip_bfloat16* vt    = (__hip_bfloat16*)alloc((size_t)E * T * 2);
    __hip_bfloat16* obuf  = xbf;  // alias: x_bf dead after QKV GEMM

    long nx8 = (long)T * E / 8;
    long nw8 = (long)E * E / 8;
    long nb8 = (long)3 * E / 8;
    long total = nx8 + 4 * nw8 + nb8;
    int pblocks = (int)((total + 255) / 256);
    prep_kernel<<<pblocks, 256, 0, stream>>>(x, Wq, Wk, Wv, Wo, bq, bk, bv,
                                             xbf, wqkv, wobf, bqkv, nx8, nw8, nb8);

    gemm_nt<true><<<dim3(3 * E / 128, T / 128), 256, 0, stream>>>(
        xbf, wqkv, bqkv, qkvb, T, 3 * E, E, 3 * E);

    rope_kernel<<<(int)(((long)T * NHEADS * 32) / 256), 256, 0, stream>>>(qkvb, cu, B, T);

    vtrans_kernel<<<(int)(((long)E * T / 8 + 255) / 256), 256, 0, stream>>>(qkvb, vt, T);

    // 256-row q-tiles: upper bound on sum of per-seq ceil(l/256)
    int qtiles_ub = T / 256 + B;
    attn_kernel<<<qtiles_ub * NHEADS, 512, 0, stream>>>(qkvb, vt, cu, obuf, B, T);

    gemm_nt<false><<<dim3(E / 128, T / 128), 256, 0, stream>>>(
        obuf, wobf, bo, d_out, T, E, E, E);
}

// Round 6
// 509.890 us; speedup vs baseline: 1.2280x; 1.1203x over previous
//
#include <hip/hip_runtime.h>
#include <hip/hip_bf16.h>
#include <cstdint>

#define E_DIM   1280
#define NHEADS  20
#define HDIM    64
#define QKV_LD  3840   // 3*E

typedef __attribute__((ext_vector_type(8))) short bf8_t;   // 8 bf16 (4 VGPRs)
typedef __attribute__((ext_vector_type(4))) short bf4_t;   // 4 bf16 (2 VGPRs)
typedef __attribute__((ext_vector_type(4))) float f4_t;    // MFMA accumulator

__device__ __forceinline__ short f2bs(float f) {
    union { __hip_bfloat16 h; short s; } u;
    u.h = __float2bfloat16(f);
    return u.s;
}

__device__ __forceinline__ f4_t mfma16x32(bf8_t a, bf8_t b, f4_t c) {
    return __builtin_amdgcn_mfma_f32_16x16x32_bf16(a, b, c, 0, 0, 0);
}
__device__ __forceinline__ f4_t mfma16x16(bf4_t a, bf4_t b, f4_t c) {
    return __builtin_amdgcn_mfma_f32_16x16x16bf16_1k(a, b, c, 0, 0, 0);
}

// async global->LDS, 16B per lane. LDS dest is wave-uniform base + lane*16.
__device__ __forceinline__ void gl_lds16(const void* g, void* l) {
    auto gp = reinterpret_cast<__attribute__((address_space(1))) unsigned int*>(
        reinterpret_cast<uintptr_t>(g));
    auto lp = reinterpret_cast<__attribute__((address_space(3))) unsigned int*>(
        reinterpret_cast<uintptr_t>(l));
    __builtin_amdgcn_global_load_lds(gp, lp, 16, 0, 0);
}

// ---------------- prep: casts + weight concat + bias concat ----------------
// Wq/bq scale = d^-0.5 * log2(e): softmax computed in base-2 domain (exp2f).
#define QSCALE 0.18033688011112042f

__device__ __forceinline__ void cvt8(__hip_bfloat16* dst, const float* src, float sc) {
    float4 a = *(const float4*)src;
    float4 b = *(const float4*)(src + 4);
    bf8_t v;
    v[0] = f2bs(a.x * sc); v[1] = f2bs(a.y * sc); v[2] = f2bs(a.z * sc); v[3] = f2bs(a.w * sc);
    v[4] = f2bs(b.x * sc); v[5] = f2bs(b.y * sc); v[6] = f2bs(b.z * sc); v[7] = f2bs(b.w * sc);
    *(bf8_t*)dst = v;
}

__global__ __launch_bounds__(256) void prep_kernel(
    const float* __restrict__ x,
    const float* __restrict__ wq, const float* __restrict__ wk,
    const float* __restrict__ wv, const float* __restrict__ wo,
    const float* __restrict__ bq, const float* __restrict__ bk, const float* __restrict__ bv,
    __hip_bfloat16* __restrict__ xbf, __hip_bfloat16* __restrict__ wqkv,
    __hip_bfloat16* __restrict__ wobf, float* __restrict__ bqkv,
    long nx8, long nw8, long nb8)
{
    long u = (long)blockIdx.x * 256 + threadIdx.x;
    if (u < nx8) { cvt8(xbf + u * 8, x + u * 8, 1.0f); return; }
    u -= nx8;
    if (u < 3 * nw8) {
        long e = u * 8;
        long w1 = nw8 * 8;
        const float* src; float sc;
        if (e < w1)            { src = wq + e;           sc = QSCALE; }
        else if (e < 2 * w1)   { src = wk + (e - w1);    sc = 1.0f; }
        else                   { src = wv + (e - 2*w1);  sc = 1.0f; }
        cvt8(wqkv + e, src, sc);
        return;
    }
    u -= 3 * nw8;
    if (u < nw8) { cvt8(wobf + u * 8, wo + u * 8, 1.0f); return; }
    u -= nw8;
    if (u < nb8) {
        long e = u * 8;
        #pragma unroll
        for (int j = 0; j < 8; j++) {
            long i = e + j;
            float v;
            if (i < E_DIM)           v = bq[i] * QSCALE;
            else if (i < 2 * E_DIM)  v = bk[i - E_DIM];
            else                     v = bv[i - 2 * E_DIM];
            bqkv[i] = v;
        }
    }
}

// ---------------- m97-style NT GEMM: C = A(MxK) * B(NxK)^T + bias ----------------
template<bool BF16_OUT>
__global__ __launch_bounds__(256, 3) void gemm_nt(
    const __hip_bfloat16* __restrict__ A, const __hip_bfloat16* __restrict__ Bw,
    const float* __restrict__ bias, void* __restrict__ Cout,
    int M, int N, int K, int ldc)
{
    __shared__ __align__(16) __hip_bfloat16 As[128 * 32];
    __shared__ __align__(16) __hip_bfloat16 Bs[128 * 32];
    const int t = threadIdx.x;
    const int wv = t >> 6;
    const int ln = t & 63;
    const int m16 = ln & 15, q4 = ln >> 4;
    const int row0 = blockIdx.y * 128, col0 = blockIdx.x * 128;
    const int wm = (wv >> 1) * 64, wn = (wv & 1) * 64;

    f4_t acc[4][4] = {};

    for (int k0 = 0; k0 < K; k0 += 32) {
        #pragma unroll
        for (int i = 0; i < 2; i++) {
            int s = i * 256 + t;
            int r = s >> 2, c = s & 3;
            gl_lds16(A + (size_t)(row0 + r) * K + k0 + c * 8,
                     As + (size_t)(i * 256 + wv * 64) * 8);
        }
        #pragma unroll
        for (int i = 0; i < 2; i++) {
            int s = i * 256 + t;
            int r = s >> 2, c = s & 3;
            gl_lds16(Bw + (size_t)(col0 + r) * K + k0 + c * 8,
                     Bs + (size_t)(i * 256 + wv * 64) * 8);
        }
        __syncthreads();
        bf8_t af[4], bfr[4];
        #pragma unroll
        for (int mt = 0; mt < 4; mt++)
            af[mt] = *(const bf8_t*)&As[(wm + mt * 16 + m16) * 32 + q4 * 8];
        #pragma unroll
        for (int nt = 0; nt < 4; nt++)
            bfr[nt] = *(const bf8_t*)&Bs[(wn + nt * 16 + m16) * 32 + q4 * 8];
        #pragma unroll
        for (int mt = 0; mt < 4; mt++)
            #pragma unroll
            for (int nt = 0; nt < 4; nt++)
                acc[mt][nt] = mfma16x32(af[mt], bfr[nt], acc[mt][nt]);
        __syncthreads();
    }

    #pragma unroll
    for (int nt = 0; nt < 4; nt++) {
        int cg = col0 + wn + nt * 16 + m16;
        float bv = bias[cg];
        #pragma unroll
        for (int mt = 0; mt < 4; mt++) {
            #pragma unroll
            for (int r = 0; r < 4; r++) {
                int rg = row0 + wm + mt * 16 + q4 * 4 + r;
                float v = acc[mt][nt][r] + bv;
                if constexpr (BF16_OUT)
                    ((__hip_bfloat16*)Cout)[(long)rg * ldc + cg] = __float2bfloat16(v);
                else
                    ((float*)Cout)[(long)rg * ldc + cg] = v;
            }
        }
    }
}

// ---------------- RoPE (in place on q,k sections of qkv) ----------------
__global__ __launch_bounds__(256) void rope_kernel(
    __hip_bfloat16* __restrict__ qkv, const int* __restrict__ cu, int B, int T)
{
    long idx = (long)blockIdx.x * 256 + threadIdx.x;
    int i = idx & 31;
    long r = idx >> 5;
    int h = (int)(r % NHEADS);
    int tok = (int)(r / NHEADS);
    if (tok >= T) return;
    int pos = tok;
    for (int b = 1; b <= B; b++) if (tok >= cu[b]) pos = tok - cu[b];
    float f = (float)pos * exp2f(-(float)i * 0.41524100558003436f);
    float s, c;
    sincosf(f, &s, &c);
    long base = (long)tok * QKV_LD + h * HDIM + i;
    {
        float q1 = __bfloat162float(qkv[base]);
        float q2 = __bfloat162float(qkv[base + 32]);
        qkv[base]      = __float2bfloat16(q1 * c - q2 * s);
        qkv[base + 32] = __float2bfloat16(q2 * c + q1 * s);
    }
    {
        long kb = base + E_DIM;
        float k1 = __bfloat162float(qkv[kb]);
        float k2 = __bfloat162float(qkv[kb + 32]);
        qkv[kb]      = __float2bfloat16(k1 * c - k2 * s);
        qkv[kb + 32] = __float2bfloat16(k2 * c + k1 * s);
    }
}

// ---------------- V transpose: (T, h, d) -> (h*d, T) ----------------
__global__ __launch_bounds__(256) void vtrans_kernel(
    const __hip_bfloat16* __restrict__ qkv, __hip_bfloat16* __restrict__ vt, int T)
{
    long u = (long)blockIdx.x * 256 + threadIdx.x;
    int tchunks = T >> 3;
    int tc = (int)(u % tchunks);
    int hd = (int)(u / tchunks);
    if (hd >= E_DIM) return;
    long t0 = (long)tc * 8;
    bf8_t v;
    #pragma unroll
    for (int j = 0; j < 8; j++)
        v[j] = *(const short*)&qkv[(t0 + j) * QKV_LD + 2 * E_DIM + hd];
    *(bf8_t*)&vt[(long)hd * T + t0] = v;
}

// ---------------- flash attention: round-2 schedule + round-3 swizzle ----------------
// 1 block (256 thr) = 128 q-rows of one (seq, head). NATURAL h-fastest block order
// + 3 blocks/CU residency: round 2 measured FETCH 74 MB (L2 lockstep sharing of KV
// tiles across same-pair q-tile blocks). XOR-swizzled global_load_lds staging:
// round 3 measured conflicts 9.2e7 -> 5.6e6. This round combines both.
// S^T = K.Q^T; P^T feeds O^T = V^T.P^T from registers.
__global__ __launch_bounds__(256, 3) void attn_kernel(
    const __hip_bfloat16* __restrict__ qkv, const __hip_bfloat16* __restrict__ vt,
    const int* __restrict__ cu, __hip_bfloat16* __restrict__ obuf, int B, int T)
{
    __shared__ __align__(16) __hip_bfloat16 Ks[128 * 64];  // [key][d] swizzled, 16 KB
    __shared__ __align__(16) __hip_bfloat16 Vs[64 * 128];  // [d][key] swizzled, 16 KB

    int idx = blockIdx.x;
    int h = idx % NHEADS;
    int gt = idx / NHEADS;
    int b = 0, l = 0, seq0 = 0;
    for (; b < B; ++b) {
        seq0 = cu[b];
        l = cu[b + 1] - seq0;
        int ntile = (l + 127) >> 7;
        if (gt < ntile) break;
        gt -= ntile;
    }
    if (b == B) return;
    int q0 = gt * 128;

    const int t = threadIdx.x;
    const int wv = t >> 6, ln = t & 63;
    const int m16 = ln & 15, q4 = ln >> 4;

    // Q B-frags in registers: bq[nt][kc] = B[k=kc*32+q4*8+j][n=m16]
    bf8_t bq[2][2];
    #pragma unroll
    for (int nt = 0; nt < 2; nt++) {
        int qrow = q0 + wv * 32 + nt * 16 + m16;
        #pragma unroll
        for (int kc = 0; kc < 2; kc++) {
            bf8_t v = (bf8_t)0;
            if (qrow < l)
                v = *(const bf8_t*)(qkv + (long)(seq0 + qrow) * QKV_LD + h * HDIM + kc * 32 + q4 * 8);
            bq[nt][kc] = v;
        }
    }

    f4_t oacc[2][4] = {};
    float m_s[2] = {-1e30f, -1e30f};
    float l_s[2] = {0.0f, 0.0f};

    const int ksw0 = (q4 ^ (m16 & 7)) * 8;        // slot of global chunk q4
    const int ksw1 = ((4 + q4) ^ (m16 & 7)) * 8;  // slot of global chunk 4+q4

    for (int kv0 = 0; kv0 < l; kv0 += 128) {
        bool full = (kv0 + 128 <= l);
        __syncthreads();
        if (full) {
            #pragma unroll
            for (int i = 0; i < 4; i++) {   // K: slot s2 -> row s2>>3, chunk (s2&7)^(row&7)
                int s2 = i * 256 + t;
                int key = s2 >> 3, cg = (s2 & 7) ^ (key & 7);
                gl_lds16(qkv + (long)(seq0 + kv0 + key) * QKV_LD + E_DIM + h * HDIM + cg * 8,
                         (char*)Ks + (size_t)(i * 256 + wv * 64) * 16);
            }
            #pragma unroll
            for (int i = 0; i < 4; i++) {   // V: slot s2 -> row s2>>4, chunk (s2&15)^(row&15)
                int s2 = i * 256 + t;
                int d = s2 >> 4, cg = (s2 & 15) ^ (d & 15);
                gl_lds16(vt + (long)(h * HDIM + d) * T + seq0 + kv0 + cg * 8,
                         (char*)Vs + (size_t)(i * 256 + wv * 64) * 16);
            }
        } else {
            #pragma unroll
            for (int i = 0; i < 4; i++) {
                int s2 = i * 256 + t;
                int key = s2 >> 3, c = s2 & 7;
                bf8_t v = (bf8_t)0;
                if (kv0 + key < l)
                    v = *(const bf8_t*)(qkv + (long)(seq0 + kv0 + key) * QKV_LD + E_DIM + h * HDIM + c * 8);
                *(bf8_t*)&Ks[key * 64 + (c ^ (key & 7)) * 8] = v;
            }
            #pragma unroll
            for (int i = 0; i < 4; i++) {
                int s2 = i * 256 + t;
                int d = s2 >> 4, c = s2 & 15;
                bf8_t v = (bf8_t)0;
                int tb = kv0 + c * 8;
                #pragma unroll
                for (int u = 0; u < 8; u++)
                    if (tb + u < l)
                        v[u] = *(const short*)&vt[(long)(h * HDIM + d) * T + seq0 + tb + u];
                *(bf8_t*)&Vs[d * 128 + (c ^ (d & 15)) * 8] = v;
            }
        }
        __syncthreads();

        // S^T = K.Q^T : S[nt][mt] holds S^T[key=mt*16+q4*4+r][qrow=m16]
        f4_t S[2][8];
        #pragma unroll
        for (int mt = 0; mt < 8; mt++) {
            const __hip_bfloat16* krow = &Ks[(mt * 16 + m16) * 64];
            bf8_t ak0 = *(const bf8_t*)(krow + ksw0);
            bf8_t ak1 = *(const bf8_t*)(krow + ksw1);
            #pragma unroll
            for (int nt = 0; nt < 2; nt++) {
                f4_t a = {};
                a = mfma16x32(ak0, bq[nt][0], a);
                a = mfma16x32(ak1, bq[nt][1], a);
                S[nt][mt] = a;
            }
        }
        if (!full) {
            #pragma unroll
            for (int mt = 0; mt < 8; mt++) {
                #pragma unroll
                for (int r = 0; r < 4; r++) {
                    bool valid = (kv0 + mt * 16 + q4 * 4 + r) < l;
                    #pragma unroll
                    for (int nt = 0; nt < 2; nt++)
                        if (!valid) S[nt][mt][r] = -1e30f;
                }
            }
        }

        // online softmax (base-2 domain; log2e folded into Wq/bq)
        #pragma unroll
        for (int nt = 0; nt < 2; nt++) {
            float mx = -1e30f;
            #pragma unroll
            for (int mt = 0; mt < 8; mt++)
                #pragma unroll
                for (int r = 0; r < 4; r++)
                    mx = fmaxf(mx, S[nt][mt][r]);
            mx = fmaxf(mx, __shfl_xor(mx, 16));
            mx = fmaxf(mx, __shfl_xor(mx, 32));
            float mn = fmaxf(m_s[nt], mx);
            float al = exp2f(m_s[nt] - mn);
            m_s[nt] = mn;
            float ls = 0.0f;
            #pragma unroll
            for (int mt = 0; mt < 8; mt++) {
                #pragma unroll
                for (int r = 0; r < 4; r++) {
                    float p = exp2f(S[nt][mt][r] - mn);
                    ls += p;
                    S[nt][mt][r] = p;
                }
            }
            l_s[nt] = l_s[nt] * al + ls;
            #pragma unroll
            for (int dt = 0; dt < 4; dt++)
                #pragma unroll
                for (int r = 0; r < 4; r++)
                    oacc[nt][dt][r] *= al;
        }

        // O^T += V^T . P^T  (A=V^T from swizzled LDS, B=P^T from regs)
        #pragma unroll
        for (int mt = 0; mt < 8; mt++) {
            bf4_t bp[2];
            #pragma unroll
            for (int nt = 0; nt < 2; nt++) {
                bf4_t p;
                p[0] = f2bs(S[nt][mt][0]); p[1] = f2bs(S[nt][mt][1]);
                p[2] = f2bs(S[nt][mt][2]); p[3] = f2bs(S[nt][mt][3]);
                bp[nt] = p;
            }
            const int vsw = ((mt * 2 + (q4 >> 1)) ^ m16) * 8 + (q4 & 1) * 4;
            #pragma unroll
            for (int dt = 0; dt < 4; dt++) {
                bf4_t av = *(const bf4_t*)&Vs[(dt * 16 + m16) * 128 + vsw];
                #pragma unroll
                for (int nt = 0; nt < 2; nt++)
                    oacc[nt][dt] = mfma16x16(av, bp[nt], oacc[nt][dt]);
            }
        }
    }

    // finalize
    #pragma unroll
    for (int nt = 0; nt < 2; nt++) {
        float ls = l_s[nt];
        ls += __shfl_xor(ls, 16);
        ls += __shfl_xor(ls, 32);
        float inv = 1.0f / ls;
        int qrow = q0 + wv * 32 + nt * 16 + m16;
        if (qrow < l) {
            #pragma unroll
            for (int dt = 0; dt < 4; dt++) {
                bf4_t o;
                #pragma unroll
                for (int r = 0; r < 4; r++)
                    o[r] = f2bs(oacc[nt][dt][r] * inv);
                *(bf4_t*)&obuf[(long)(seq0 + qrow) * E_DIM + h * HDIM + dt * 16 + q4 * 4] = o;
            }
        }
    }
}

// ---------------- launch ----------------
extern "C" void kernel_launch(void* const* d_in, const int* in_sizes, int n_in,
                              void* d_out, int out_size, void* d_ws, size_t ws_size,
                              hipStream_t stream) {
    const int E = E_DIM;
    const int T = in_sizes[0] / E;      // 8192
    const int B = in_sizes[1] - 1;      // 8

    const float* x  = (const float*)d_in[0];
    const int*   cu = (const int*)d_in[1];
    const float* Wq = (const float*)d_in[3];
    const float* bq = (const float*)d_in[4];
    const float* Wk = (const float*)d_in[5];
    const float* bk = (const float*)d_in[6];
    const float* Wv = (const float*)d_in[7];
    const float* bv = (const float*)d_in[8];
    const float* Wo = (const float*)d_in[9];
    const float* bo = (const float*)d_in[10];

    char* ws = (char*)d_ws;
    size_t off = 0;
    auto alloc = [&](size_t bytes) -> void* {
        void* p = ws + off;
        off = (off + bytes + 255) & ~(size_t)255;
        return p;
    };
    __hip_bfloat16* xbf   = (__hip_bfloat16*)alloc((size_t)T * E * 2);
    __hip_bfloat16* wqkv  = (__hip_bfloat16*)alloc((size_t)3 * E * E * 2);
    __hip_bfloat16* wobf  = (__hip_bfloat16*)alloc((size_t)E * E * 2);
    float*          bqkv  = (float*)alloc((size_t)3 * E * 4);
    __hip_bfloat16* qkvb  = (__hip_bfloat16*)alloc((size_t)T * 3 * E * 2);
    __hip_bfloat16* vt    = (__hip_bfloat16*)alloc((size_t)E * T * 2);
    __hip_bfloat16* obuf  = xbf;  // alias: x_bf dead after QKV GEMM

    long nx8 = (long)T * E / 8;
    long nw8 = (long)E * E / 8;
    long nb8 = (long)3 * E / 8;
    long total = nx8 + 4 * nw8 + nb8;
    int pblocks = (int)((total + 255) / 256);
    prep_kernel<<<pblocks, 256, 0, stream>>>(x, Wq, Wk, Wv, Wo, bq, bk, bv,
                                             xbf, wqkv, wobf, bqkv, nx8, nw8, nb8);

    gemm_nt<true><<<dim3(3 * E / 128, T / 128), 256, 0, stream>>>(
        xbf, wqkv, bqkv, qkvb, T, 3 * E, E, 3 * E);

    rope_kernel<<<(int)(((long)T * NHEADS * 32) / 256), 256, 0, stream>>>(qkvb, cu, B, T);

    vtrans_kernel<<<(int)(((long)E * T / 8 + 255) / 256), 256, 0, stream>>>(qkvb, vt, T);

    // 128-row q-tiles: upper bound on sum of per-seq ceil(l/128)
    int qtiles_ub = T / 128 + B;
    attn_kernel<<<qtiles_ub * NHEADS, 256, 0, stream>>>(qkvb, vt, cu, obuf, B, T);

    gemm_nt<false><<<dim3(E / 128, T / 128), 256, 0, stream>>>(
        obuf, wobf, bo, d_out, T, E, E, E);
}